// Round 1
// baseline (493.617 us; speedup 1.0000x reference)
//
#include <hip/hip_runtime.h>

// BatchGroupItN: iterative whitening (IterNorm) over G=32 groups (g = c % 32).
// x: (64,256,56,56) fp32.  m = 512*3136 per group.
// Phase 1: Gram(32x32) + per-group sums (atomic accum in ws).
// Phase 2: sigma -> Newton-Schulz(5) -> wmT + shift (tiny, 1 block).
// Phase 3: out = (wm @ (x - mu)) * weight + bias, streaming.

#define EPS 1e-5f
#define NS_ITERS 5
#define HW_ 3136            // 56*56
#define PANELS 512          // N * C/32 = 64*8
#define PANEL_STRIDE 100352 // 32*3136 elements per panel
#define M_COLS 1605632.0f   // 512*3136
#define TPP 49              // 64-col tiles per panel (3136/64)
#define TILES_TOTAL 25088   // PANELS*TPP
#define NB1 1024            // phase-1 grid

// ws layout (floats)
#define WS_GRAM 0
#define WS_SUM 1024
#define WS_WMT 1056
#define WS_SHIFT 2080

// ---------------- Phase 1: stats (Gram + sums) ----------------
__global__ __launch_bounds__(256) void k_stats(const float* __restrict__ x,
                                               float* __restrict__ ws) {
  __shared__ float smem[4096]; // 16 KiB: tile V[32][64] (swizzled) + reduction scratch
  const int tid = threadIdx.x;
  const int sub = tid >> 4;        // 16 subgroups, 4 columns each
  const int t16 = tid & 15;
  const int ti = t16 >> 2, tj = t16 & 3; // 4x4 thread grid -> 8x8 reg tile
  const int c0 = sub << 2;
  const int row0 = tid >> 4;       // staging row (0..15), +16 for second load
  const int c4 = tid & 15;

  // swizzle: phys_col = (col + 16*((row>>3)&1)) & 63  -> <=2-way LDS conflicts
  const int physA = (c0 + ((ti & 1) << 4)) & 63;
  const int physB = (c0 + ((tj & 1) << 4)) & 63;
  const int sw0 = ((c4 << 2) + (((row0 >> 3) & 1) << 4)) & 63; // rows r and r+16 share parity

  float acc[8][8];
#pragma unroll
  for (int i = 0; i < 8; ++i)
#pragma unroll
    for (int j = 0; j < 8; ++j) acc[i][j] = 0.0f;
  float sum_lo = 0.0f, sum_hi = 0.0f;

  for (int t = blockIdx.x; t < TILES_TOTAL; t += gridDim.x) {
    const int panel = t / TPP;
    const int tin = t - panel * TPP;
    const unsigned base = (unsigned)panel * PANEL_STRIDE + ((unsigned)tin << 6);
    const float4 v0 = *(const float4*)(x + base + row0 * HW_ + (c4 << 2));
    const float4 v1 = *(const float4*)(x + base + (row0 + 16) * HW_ + (c4 << 2));
    __syncthreads(); // previous tile's compute reads done
    *(float4*)(smem + (row0 << 6) + sw0) = v0;
    *(float4*)(smem + ((row0 + 16) << 6) + sw0) = v1;
    sum_lo += v0.x + v0.y + v0.z + v0.w;
    sum_hi += v1.x + v1.y + v1.z + v1.w;
    __syncthreads();

    float4 a4[8], b4[8];
#pragma unroll
    for (int i = 0; i < 8; ++i)
      a4[i] = *(const float4*)(smem + (((ti << 3) + i) << 6) + physA);
#pragma unroll
    for (int j = 0; j < 8; ++j)
      b4[j] = *(const float4*)(smem + (((tj << 3) + j) << 6) + physB);
#pragma unroll
    for (int i = 0; i < 8; ++i)
#pragma unroll
      for (int j = 0; j < 8; ++j) {
        acc[i][j] += a4[i].x * b4[j].x + a4[i].y * b4[j].y +
                     a4[i].z * b4[j].z + a4[i].w * b4[j].w;
      }
  }

  // block reduction across 16 subgroups -> atomicAdd into ws gram
  for (int r = 0; r < 4; ++r) {
    __syncthreads();
#pragma unroll
    for (int q = 0; q < 16; ++q) {
      const int a = r * 16 + q;
      smem[q * 256 + tid] = acc[a >> 3][a & 7];
    }
    __syncthreads();
    const int q = tid >> 4, tt = tid & 15;
    float s = 0.0f;
#pragma unroll
    for (int sg = 0; sg < 16; ++sg) s += smem[q * 256 + sg * 16 + tt];
    const int a = r * 16 + q;
    const int row = ((tt >> 2) << 3) + (a >> 3);
    const int col = ((tt & 3) << 3) + (a & 7);
    atomicAdd(ws + WS_GRAM + row * 32 + col, s);
  }

  // sums
  __syncthreads();
  smem[tid] = sum_lo;
  smem[256 + tid] = sum_hi;
  __syncthreads();
  if (tid < 32) {
    const int base = (tid < 16) ? (tid * 16) : (256 + (tid - 16) * 16);
    float s = 0.0f;
#pragma unroll
    for (int k = 0; k < 16; ++k) s += smem[base + k];
    atomicAdd(ws + WS_SUM + tid, s);
  }
}

// ---------------- Phase 2: Newton-Schulz (1 block) ----------------
__global__ __launch_bounds__(1024) void k_ns(float* __restrict__ ws,
                                             const float* __restrict__ weight,
                                             const float* __restrict__ bias) {
  __shared__ float Pm[32 * 33], SN[32 * 33], T1[32 * 33], T2[32 * 33];
  __shared__ float meanb[32], ms[32], misc[1];
  const int tid = threadIdx.x;
  const int i = tid >> 5, j = tid & 31;
  const float inv_m = 1.0f / M_COLS;

  const float gv = ws[WS_GRAM + tid];
  if (tid < 32) meanb[tid] = ws[WS_SUM + tid] * inv_m;
  __syncthreads();
  const float sig = gv * inv_m - meanb[i] * meanb[j] + ((i == j) ? EPS : 0.0f);
  T1[i * 33 + j] = sig;
  __syncthreads();
  if (tid == 0) {
    float tr = 0.0f;
    for (int k = 0; k < 32; ++k) tr += T1[k * 33 + k];
    misc[0] = 1.0f / tr;
  }
  __syncthreads();
  const float tinv = misc[0];
  SN[i * 33 + j] = sig * tinv;
  Pm[i * 33 + j] = (i == j) ? 1.0f : 0.0f;
  __syncthreads();

  for (int it = 0; it < NS_ITERS; ++it) {
    float a = 0.0f;
    for (int k = 0; k < 32; ++k) a += Pm[i * 33 + k] * Pm[k * 33 + j];
    T1[i * 33 + j] = a;
    __syncthreads();
    float b = 0.0f;
    for (int k = 0; k < 32; ++k) b += T1[i * 33 + k] * Pm[k * 33 + j];
    T2[i * 33 + j] = b;
    __syncthreads();
    float c = 0.0f;
    for (int k = 0; k < 32; ++k) c += T2[i * 33 + k] * SN[k * 33 + j];
    const float pn = 1.5f * Pm[i * 33 + j] - 0.5f * c;
    __syncthreads();
    Pm[i * 33 + j] = pn;
    __syncthreads();
  }

  const float sq = sqrtf(tinv);
  const float wmv = Pm[i * 33 + j] * sq;    // wm[i][j]
  ws[WS_WMT + j * 32 + i] = wmv;            // transposed: [g'][g]
  T1[i * 33 + j] = wmv;
  __syncthreads();
  if (j == 0) {
    float s = 0.0f;
    for (int k = 0; k < 32; ++k) s += T1[i * 33 + k] * meanb[k];
    ms[i] = s; // mshift[g] = sum_g' wm[g][g'] * mean[g']
  }
  __syncthreads();
  if (tid < 256) {
    ws[WS_SHIFT + tid] = bias[tid] - weight[tid] * ms[tid & 31];
  }
}

// ---------------- Phase 3: apply ----------------
__global__ __launch_bounds__(256) void k_apply(const float* __restrict__ x,
                                               const float* __restrict__ weight,
                                               const float* __restrict__ ws,
                                               float* __restrict__ out) {
  __shared__ float wmT[1024];
  __shared__ float wt[256], sh[256];
  const int tid = threadIdx.x;
  *(float4*)(wmT + tid * 4) = *(const float4*)(ws + WS_WMT + tid * 4);
  wt[tid] = weight[tid];
  sh[tid] = ws[WS_SHIFT + tid];
  __syncthreads();

  unsigned base[4];
  int cb[4];
#pragma unroll
  for (int k = 0; k < 4; ++k) {
    const unsigned J = blockIdx.x * 1024u + (unsigned)tid + (unsigned)k * 256u;
    const unsigned panel = J / HW_;
    const unsigned p = J - panel * HW_;
    base[k] = panel * PANEL_STRIDE + p;
    cb[k] = (int)(panel & 7u) * 32;
  }

  float acc[32][4];
#pragma unroll
  for (int g = 0; g < 32; ++g) {
    acc[g][0] = 0.0f; acc[g][1] = 0.0f; acc[g][2] = 0.0f; acc[g][3] = 0.0f;
  }

  for (int gp = 0; gp < 32; ++gp) {
    const float v0 = x[base[0] + gp * HW_];
    const float v1 = x[base[1] + gp * HW_];
    const float v2 = x[base[2] + gp * HW_];
    const float v3 = x[base[3] + gp * HW_];
#pragma unroll
    for (int gc = 0; gc < 8; ++gc) {
      const float4 wv = *(const float4*)(wmT + (gp << 5) + (gc << 2));
      const float wvr[4] = {wv.x, wv.y, wv.z, wv.w};
#pragma unroll
      for (int cc = 0; cc < 4; ++cc) {
        const int g = gc * 4 + cc;
        acc[g][0] += wvr[cc] * v0;
        acc[g][1] += wvr[cc] * v1;
        acc[g][2] += wvr[cc] * v2;
        acc[g][3] += wvr[cc] * v3;
      }
    }
  }

#pragma unroll
  for (int g = 0; g < 32; ++g) {
#pragma unroll
    for (int k = 0; k < 4; ++k) {
      const int c = cb[k] + g;
      out[base[k] + g * HW_] = acc[g][k] * wt[c] + sh[c];
    }
  }
}

extern "C" void kernel_launch(void* const* d_in, const int* in_sizes, int n_in,
                              void* d_out, int out_size, void* d_ws, size_t ws_size,
                              hipStream_t stream) {
  const float* x = (const float*)d_in[0];
  const float* w = (const float*)d_in[1];
  const float* b = (const float*)d_in[2];
  float* out = (float*)d_out;
  float* ws = (float*)d_ws;

  // zero the atomic accumulators (gram 1024 + sums 32)
  hipMemsetAsync(d_ws, 0, (1024 + 32) * sizeof(float), stream);
  hipLaunchKernelGGL(k_stats, dim3(NB1), dim3(256), 0, stream, x, ws);
  hipLaunchKernelGGL(k_ns, dim3(1), dim3(1024), 0, stream, ws, w, b);
  hipLaunchKernelGGL(k_apply, dim3(1568), dim3(256), 0, stream, x, w, ws, out);
}

// Round 2
// 416.983 us; speedup vs baseline: 1.1838x; 1.1838x over previous
//
#include <hip/hip_runtime.h>

// BatchGroupItN: iterative whitening over G=32 groups (g = c % 32).
// x: (64,256,56,56) fp32.  m = 512*3136 per group.
// Phase 1 (k_stats): bf16 MFMA Gram(32x32) + fp32 per-group sums -> atomics in ws.
// Phase 2 (k_ns): sigma -> Newton-Schulz(5) -> wmT + shift. 1 wave.
// Phase 3 (k_apply): out = (wm @ (x - mu)) * weight + bias. Spill-free scalar.

#define EPS 1e-5f
#define NS_ITERS 5
#define HW_ 3136            // 56*56
#define PANELS 512          // N * C/32 = 64*8
#define PANEL_STRIDE 100352 // 32*3136 elements per panel
#define M_COLS 1605632.0f   // 512*3136
#define TPP 49              // 64-col tiles per panel (3136/64)
#define TILES_TOTAL 25088   // PANELS*TPP
#define NB1 512             // phase-1 grid (25088/512 = 49 tiles/block exactly)

// ws layout (floats)
#define WS_GRAM 0
#define WS_SUM 1024
#define WS_WMT 1056
#define WS_SHIFT 2080

typedef __attribute__((ext_vector_type(4))) float f32x4;
typedef __attribute__((ext_vector_type(8))) short short8v;

__device__ __forceinline__ unsigned f2bf2(float a, float b) {
  unsigned ua = __float_as_uint(a); ua = (ua + 0x7FFFu + ((ua >> 16) & 1u)) >> 16;
  unsigned ub = __float_as_uint(b); ub = (ub + 0x7FFFu + ((ub >> 16) & 1u)) >> 16;
  return ua | (ub << 16);
}

// bf16 tile [32 rows][64 pos], row = 128B. 16B slots XOR+rotate swizzled so
// fragment reads (32 rows at one slot) and staging writes sit at the LDS
// bandwidth floor (no >floor bank conflicts).
__device__ __forceinline__ int swzbyte(int r, int slotq) {
  const int ph = (((slotq) ^ (r & 7)) + 2 * (r >> 3)) & 7;
  return r * 128 + ph * 16;
}

// ---------------- Phase 1: stats (bf16 MFMA Gram + fp32 sums) ----------------
__global__ __launch_bounds__(256) void k_stats(const float* __restrict__ x,
                                               float* __restrict__ ws) {
  __shared__ __align__(16) float smem[2048]; // 8KB: bf16 tile (4KB) / reduce scratch
  unsigned short* tile = (unsigned short*)smem;
  const int tid = threadIdx.x;
  const int row_w = tid >> 4;   // staging rows: row_w and row_w+16
  const int c4 = tid & 15;
  const int pos = c4 << 2;
  const int wv = tid >> 6;      // wave 0..3
  const int lane = tid & 63;

  const int wa_lo = swzbyte(row_w, pos >> 3) + (pos & 7) * 2;
  const int wa_hi = swzbyte(row_w + 16, pos >> 3) + (pos & 7) * 2;

  // fragment addrs: wave w covers position chunk (w>>1)*32..+31 (K=32),
  // lane l: row = (l&15) [+16], pos = chunk*32 + (l>>4)*8 -> slotq = chunk*4 + (l>>4)
  const int fr_r = lane & 15;
  const int fr_sq = (wv >> 1) * 4 + (lane >> 4);
  const int ra0 = swzbyte(fr_r, fr_sq);
  const int ra1 = swzbyte(fr_r + 16, fr_sq);
  const bool bsel = (wv & 1);   // B operand = rows half (w&1) -> gram col half

  f32x4 acc0 = {0.f, 0.f, 0.f, 0.f};  // gram quad (rows 0-15, cols bsel*16..)
  f32x4 acc1 = {0.f, 0.f, 0.f, 0.f};  // gram quad (rows 16-31, cols bsel*16..)
  float sum_lo = 0.f, sum_hi = 0.f;

  for (int t = blockIdx.x; t < TILES_TOTAL; t += gridDim.x) {
    const int panel = t / TPP;
    const int tin = t - panel * TPP;
    const unsigned base = (unsigned)panel * PANEL_STRIDE + ((unsigned)tin << 6);
    const float4 v0 = *(const float4*)(x + base + row_w * HW_ + pos);
    const float4 v1 = *(const float4*)(x + base + (row_w + 16) * HW_ + pos);
    __syncthreads(); // previous tile's fragment reads done
    *(uint2*)((char*)tile + wa_lo) = make_uint2(f2bf2(v0.x, v0.y), f2bf2(v0.z, v0.w));
    *(uint2*)((char*)tile + wa_hi) = make_uint2(f2bf2(v1.x, v1.y), f2bf2(v1.z, v1.w));
    sum_lo += v0.x + v0.y + v0.z + v0.w;
    sum_hi += v1.x + v1.y + v1.z + v1.w;
    __syncthreads();
    const short8v f0 = *(const short8v*)((char*)tile + ra0);
    const short8v f1 = *(const short8v*)((char*)tile + ra1);
    const short8v fB = bsel ? f1 : f0;
    acc0 = __builtin_amdgcn_mfma_f32_16x16x32_bf16(f0, fB, acc0, 0, 0, 0);
    acc1 = __builtin_amdgcn_mfma_f32_16x16x32_bf16(f1, fB, acc1, 0, 0, 0);
  }

  // ---- gram reduction: 4 waves x 512 floats -> 8KB smem ----
  __syncthreads(); // all fragment reads of last tile done (tile dies here)
  {
    float* dst = smem + wv * 512 + lane * 8;
#pragma unroll
    for (int r = 0; r < 4; ++r) { dst[r] = acc0[r]; dst[4 + r] = acc1[r]; }
  }
  __syncthreads();
  // entry (R,C): from waves w = (C>>4) and (C>>4)+2;
  // C/D layout: col = lane&15, row = (lane>>4)*4 + reg (acc1 regs at +4)
#pragma unroll
  for (int q = 0; q < 4; ++q) {
    const int e = q * 256 + tid;
    const int R = e >> 5, C = e & 31;
    const int cbh = C >> 4;
    const int ln = (((R & 15) >> 2) << 4) | (C & 15);
    const int idx = ((R >> 4) << 2) | (R & 3);
    const float s = smem[cbh * 512 + ln * 8 + idx] + smem[(cbh + 2) * 512 + ln * 8 + idx];
    atomicAdd(ws + WS_GRAM + e, s);
  }

  // ---- per-group sums (fp32, exact) ----
  __syncthreads();
  smem[tid] = sum_lo;
  smem[256 + tid] = sum_hi;
  __syncthreads();
  if (tid < 32) {
    const int base2 = (tid < 16) ? tid * 16 : 256 + (tid - 16) * 16;
    float s = 0.f;
#pragma unroll
    for (int k = 0; k < 16; ++k) s += smem[base2 + k];
    atomicAdd(ws + WS_SUM + tid, s);
  }
}

// ---------------- Phase 2: Newton-Schulz (1 wave) ----------------
__device__ __forceinline__ void mm32(float* __restrict__ D, const float* __restrict__ A,
                                     const float* __restrict__ B, int i, int cbase) {
  f32x4 a0 = {0.f,0.f,0.f,0.f}, a1 = a0, a2 = a0, a3 = a0;
#pragma unroll
  for (int k = 0; k < 32; ++k) {
    const float av = A[i * 36 + k];
    const float4 b0 = *(const float4*)(B + k * 36 + cbase);
    const float4 b1 = *(const float4*)(B + k * 36 + cbase + 4);
    const float4 b2 = *(const float4*)(B + k * 36 + cbase + 8);
    const float4 b3 = *(const float4*)(B + k * 36 + cbase + 12);
    a0[0] += av * b0.x; a0[1] += av * b0.y; a0[2] += av * b0.z; a0[3] += av * b0.w;
    a1[0] += av * b1.x; a1[1] += av * b1.y; a1[2] += av * b1.z; a1[3] += av * b1.w;
    a2[0] += av * b2.x; a2[1] += av * b2.y; a2[2] += av * b2.z; a2[3] += av * b2.w;
    a3[0] += av * b3.x; a3[1] += av * b3.y; a3[2] += av * b3.z; a3[3] += av * b3.w;
  }
  float* d = D + i * 36 + cbase;
#pragma unroll
  for (int r = 0; r < 4; ++r) { d[r] = a0[r]; d[4 + r] = a1[r]; d[8 + r] = a2[r]; d[12 + r] = a3[r]; }
}

__global__ __launch_bounds__(64) void k_ns(float* __restrict__ ws,
                                           const float* __restrict__ weight,
                                           const float* __restrict__ bias) {
  __shared__ float P[32 * 36], S[32 * 36], T1[32 * 36], T2[32 * 36];
  __shared__ float mean[32], msv[64], misc[1];
  const int lane = threadIdx.x;
  const int i = lane & 31;
  const int cbase = (lane >> 5) * 16; // this lane owns row i, cols cbase..cbase+15
  const float inv_m = 1.0f / M_COLS;

  if (lane < 32) mean[lane] = ws[WS_SUM + lane] * inv_m;
  __syncthreads();
#pragma unroll
  for (int q = 0; q < 16; ++q) {
    const int e = q * 64 + lane;
    const int R = e >> 5, C = e & 31;
    S[R * 36 + C] = ws[WS_GRAM + e] * inv_m - mean[R] * mean[C] + ((R == C) ? EPS : 0.f);
  }
  __syncthreads();
  if (lane == 0) {
    float tr = 0.f;
#pragma unroll
    for (int k = 0; k < 32; ++k) tr += S[k * 36 + k];
    misc[0] = 1.0f / tr;
  }
  __syncthreads();
  const float tinv = misc[0];
#pragma unroll
  for (int q = 0; q < 16; ++q) {
    const int e = q * 64 + lane;
    const int R = e >> 5, C = e & 31;
    S[R * 36 + C] *= tinv;
    P[R * 36 + C] = (R == C) ? 1.f : 0.f;
  }
  __syncthreads();

  for (int it = 0; it < NS_ITERS; ++it) {
    mm32(T1, P, P, i, cbase);   // T1 = P^2
    __syncthreads();
    mm32(T2, T1, P, i, cbase);  // T2 = P^3
    __syncthreads();
    mm32(T1, T2, S, i, cbase);  // T1 = P^3 @ sigma_N
    __syncthreads();
#pragma unroll
    for (int cc = 0; cc < 16; ++cc) {
      const int c = cbase + cc;
      P[i * 36 + c] = 1.5f * P[i * 36 + c] - 0.5f * T1[i * 36 + c];
    }
    __syncthreads();
  }

  const float sq = sqrtf(tinv);
  float part = 0.f;
#pragma unroll
  for (int cc = 0; cc < 16; ++cc) {
    const int c = cbase + cc;
    const float wmv = P[i * 36 + c] * sq;   // wm[i][c]
    ws[WS_WMT + c * 32 + i] = wmv;          // transposed: wmT[gp][g]
    part += wmv * mean[c];
  }
  msv[lane] = part;
  __syncthreads();
#pragma unroll
  for (int q = 0; q < 4; ++q) {
    const int c = q * 64 + lane;
    const float m2 = msv[c & 31] + msv[32 + (c & 31)]; // ms[g] = sum_gp wm[g][gp]*mean[gp]
    ws[WS_SHIFT + c] = bias[c] - weight[c] * m2;
  }
}

// ---------------- Phase 3: apply (spill-free) ----------------
__global__ __launch_bounds__(256, 4) void k_apply(const float* __restrict__ x,
                                                  const float* __restrict__ weight,
                                                  const float* __restrict__ ws,
                                                  float* __restrict__ out) {
  __shared__ float wmT[1024];   // [gp][g]
  __shared__ float wt[256], sh[256];
  const int tid = threadIdx.x;
  *(float4*)(wmT + tid * 4) = *(const float4*)(ws + WS_WMT + tid * 4);
  wt[tid] = weight[tid];
  sh[tid] = ws[WS_SHIFT + tid];
  __syncthreads();

  // 2 consecutive positions per thread; pairs never cross a panel (3136 even).
  const unsigned J = blockIdx.x * 512u + (unsigned)tid * 2u;
  const unsigned panel = J / HW_;
  const unsigned p = J - panel * HW_;
  const unsigned base = panel * PANEL_STRIDE + p;
  const int cb = (int)(panel & 7u) * 32;

  float2 acc[32];
#pragma unroll
  for (int g = 0; g < 32; ++g) { acc[g].x = 0.f; acc[g].y = 0.f; }

#pragma unroll 4
  for (int gp = 0; gp < 32; ++gp) {
    const float2 v = *(const float2*)(x + base + gp * HW_);
#pragma unroll
    for (int g4 = 0; g4 < 8; ++g4) {
      const float4 w = *(const float4*)(wmT + gp * 32 + g4 * 4); // uniform broadcast
      acc[g4 * 4 + 0].x += w.x * v.x; acc[g4 * 4 + 0].y += w.x * v.y;
      acc[g4 * 4 + 1].x += w.y * v.x; acc[g4 * 4 + 1].y += w.y * v.y;
      acc[g4 * 4 + 2].x += w.z * v.x; acc[g4 * 4 + 2].y += w.z * v.y;
      acc[g4 * 4 + 3].x += w.w * v.x; acc[g4 * 4 + 3].y += w.w * v.y;
    }
  }

#pragma unroll
  for (int g = 0; g < 32; ++g) {
    const int c = cb + g;
    float2 o;
    o.x = acc[g].x * wt[c] + sh[c];
    o.y = acc[g].y * wt[c] + sh[c];
    *(float2*)(out + base + g * HW_) = o;
  }
}

extern "C" void kernel_launch(void* const* d_in, const int* in_sizes, int n_in,
                              void* d_out, int out_size, void* d_ws, size_t ws_size,
                              hipStream_t stream) {
  const float* x = (const float*)d_in[0];
  const float* w = (const float*)d_in[1];
  const float* b = (const float*)d_in[2];
  float* out = (float*)d_out;
  float* ws = (float*)d_ws;

  // zero the atomic accumulators (gram 1024 + sums 32)
  hipMemsetAsync(d_ws, 0, (1024 + 32) * sizeof(float), stream);
  hipLaunchKernelGGL(k_stats, dim3(NB1), dim3(256), 0, stream, x, ws);
  hipLaunchKernelGGL(k_ns, dim3(1), dim3(64), 0, stream, ws, w, b);
  hipLaunchKernelGGL(k_apply, dim3(3136), dim3(256), 0, stream, x, w, ws, out);
}

// Round 5
// 399.068 us; speedup vs baseline: 1.2369x; 1.0449x over previous
//
#include <hip/hip_runtime.h>

// BatchGroupItN: iterative whitening over G=32 groups (g = c % 32).
// x: (64,256,56,56) fp32.  m = 512*3136 per group.
// Phase 1 (k_stats): bf16 MFMA Gram(32x32) + fp32 sums -> per-block partials (no atomics).
// Phase 1b (k_reduce): 1024 partial vectors -> 8 chunk partials per entry.
// Phase 2 (k_ns): reduce chunks, sigma -> Newton-Schulz(5) -> wmT + shift. 2 waves.
// Phase 3 (k_apply): out = (wm @ (x - mu)) * weight + bias, nontemporal stores.

#define EPS 1e-5f
#define NS_ITERS 5
#define HW_ 3136            // 56*56
#define PANELS 512          // N * C/32 = 64*8
#define PANEL_STRIDE 100352 // 32*3136 elements per panel
#define M_COLS 1605632.0f   // 512*3136
#define TPP 49              // 64-col tiles per panel (3136/64)
#define TILES_TOTAL 25088   // PANELS*TPP
#define NB1 1024            // phase-1 grid (grid-stride, 24-25 tiles/block)

// ws layout (floats)
#define WS_GRAM 0           // (unused as accumulator now; finals live in PART2 path)
#define WS_SUM 1024
#define WS_WMT 1056
#define WS_SHIFT 2080
#define WS_PART2 4096       // 8 chunks x 1056
#define WS_PART 16384       // 1024 blocks x 1056

typedef __attribute__((ext_vector_type(4))) float f32x4;
typedef __attribute__((ext_vector_type(2))) float f32x2v;
typedef __attribute__((ext_vector_type(8))) short short8v;

__device__ __forceinline__ unsigned f2bf2(float a, float b) {
  unsigned ua = __float_as_uint(a); ua = (ua + 0x7FFFu + ((ua >> 16) & 1u)) >> 16;
  unsigned ub = __float_as_uint(b); ub = (ub + 0x7FFFu + ((ub >> 16) & 1u)) >> 16;
  return ua | (ub << 16);
}

// bf16 tile [32 rows][64 pos], row = 128B, 16B slots XOR+rotate swizzled.
__device__ __forceinline__ int swzbyte(int r, int slotq) {
  const int ph = (((slotq) ^ (r & 7)) + 2 * (r >> 3)) & 7;
  return r * 128 + ph * 16;
}

// ---------------- Phase 1: stats (bf16 MFMA Gram + fp32 sums) ----------------
__global__ __launch_bounds__(256) void k_stats(const float* __restrict__ x,
                                               float* __restrict__ ws) {
  __shared__ __align__(16) float smem[2048]; // 8KB: bf16 tile (4KB) / reduce scratch
  unsigned short* tile = (unsigned short*)smem;
  const int tid = threadIdx.x;
  const int row_w = tid >> 4;   // staging rows: row_w and row_w+16
  const int c4 = tid & 15;
  const int pos = c4 << 2;
  const int wv = tid >> 6;      // wave 0..3
  const int lane = tid & 63;

  const int wa_lo = swzbyte(row_w, pos >> 3) + (pos & 7) * 2;
  const int wa_hi = swzbyte(row_w + 16, pos >> 3) + (pos & 7) * 2;

  // fragment addrs: wave w covers position chunk (w>>1)*32..+31 (K=32),
  // lane l: row = (l&15) [+16], slotq = chunk*4 + (l>>4)
  const int fr_r = lane & 15;
  const int fr_sq = (wv >> 1) * 4 + (lane >> 4);
  const int ra0 = swzbyte(fr_r, fr_sq);
  const int ra1 = swzbyte(fr_r + 16, fr_sq);
  const bool bsel = (wv & 1);   // B operand rows half -> gram col half

  f32x4 acc0 = {0.f, 0.f, 0.f, 0.f};  // gram quad (rows 0-15, cols bsel*16..)
  f32x4 acc1 = {0.f, 0.f, 0.f, 0.f};  // gram quad (rows 16-31, cols bsel*16..)
  float sum_lo = 0.f, sum_hi = 0.f;

  for (int t = blockIdx.x; t < TILES_TOTAL; t += gridDim.x) {
    const int panel = t / TPP;
    const int tin = t - panel * TPP;
    const unsigned base = (unsigned)panel * PANEL_STRIDE + ((unsigned)tin << 6);
    const float4 v0 = *(const float4*)(x + base + row_w * HW_ + pos);
    const float4 v1 = *(const float4*)(x + base + (row_w + 16) * HW_ + pos);
    __syncthreads(); // previous tile's fragment reads done
    *(uint2*)((char*)tile + wa_lo) = make_uint2(f2bf2(v0.x, v0.y), f2bf2(v0.z, v0.w));
    *(uint2*)((char*)tile + wa_hi) = make_uint2(f2bf2(v1.x, v1.y), f2bf2(v1.z, v1.w));
    sum_lo += v0.x + v0.y + v0.z + v0.w;
    sum_hi += v1.x + v1.y + v1.z + v1.w;
    __syncthreads();
    const short8v f0 = *(const short8v*)((char*)tile + ra0);
    const short8v f1 = *(const short8v*)((char*)tile + ra1);
    const short8v fB = bsel ? f1 : f0;
    acc0 = __builtin_amdgcn_mfma_f32_16x16x32_bf16(f0, fB, acc0, 0, 0, 0);
    acc1 = __builtin_amdgcn_mfma_f32_16x16x32_bf16(f1, fB, acc1, 0, 0, 0);
  }

  // ---- gram reduction: 4 waves x 512 floats -> 8KB smem ----
  __syncthreads(); // all fragment reads of last tile done (tile dies here)
  {
    float* dst = smem + wv * 512 + lane * 8;
#pragma unroll
    for (int r = 0; r < 4; ++r) { dst[r] = acc0[r]; dst[4 + r] = acc1[r]; }
  }
  __syncthreads();
  float* part = ws + WS_PART + (unsigned)blockIdx.x * 1056u;
  // entry (R,C): from waves w = (C>>4) and (C>>4)+2;
  // C/D layout: col = lane&15, row = (lane>>4)*4 + reg (acc1 regs at +4)
#pragma unroll
  for (int q = 0; q < 4; ++q) {
    const int e = q * 256 + tid;
    const int R = e >> 5, C = e & 31;
    const int cbh = C >> 4;
    const int ln = (((R & 15) >> 2) << 4) | (C & 15);
    const int idx = ((R >> 4) << 2) | (R & 3);
    part[e] = smem[cbh * 512 + ln * 8 + idx] + smem[(cbh + 2) * 512 + ln * 8 + idx];
  }

  // ---- per-group sums (fp32, exact) ----
  __syncthreads();
  smem[tid] = sum_lo;
  smem[256 + tid] = sum_hi;
  __syncthreads();
  if (tid < 32) {
    const int base2 = (tid < 16) ? tid * 16 : 256 + (tid - 16) * 16;
    float s = 0.f;
#pragma unroll
    for (int k = 0; k < 16; ++k) s += smem[base2 + k];
    part[1024 + tid] = s;
  }
}

// ---------------- Phase 1b: partial reduction (1024 -> 8 per entry) ----------------
__global__ __launch_bounds__(256) void k_reduce(float* __restrict__ ws) {
  const int gid = blockIdx.x * 256 + threadIdx.x; // 0..8447
  const int chunk = gid / 1056;                    // 0..7
  const int e = gid - chunk * 1056;                // 0..1055
  const float* src = ws + WS_PART + e + (unsigned)chunk * 128u * 1056u;
  float s = 0.f;
#pragma unroll 8
  for (int b = 0; b < 128; ++b) s += src[(unsigned)b * 1056u];
  ws[WS_PART2 + chunk * 1056 + e] = s;
}

// ---------------- Phase 2: Newton-Schulz (2 waves) ----------------
__device__ __forceinline__ void mm32(float* __restrict__ D, const float* __restrict__ A,
                                     const float* __restrict__ B, int i, int cbase) {
  float a0[4] = {0.f, 0.f, 0.f, 0.f}, a1[4] = {0.f, 0.f, 0.f, 0.f};
#pragma unroll
  for (int k = 0; k < 32; ++k) {
    const float av = A[i * 36 + k];
    const float4 b0 = *(const float4*)(B + k * 36 + cbase);
    const float4 b1 = *(const float4*)(B + k * 36 + cbase + 4);
    a0[0] += av * b0.x; a0[1] += av * b0.y; a0[2] += av * b0.z; a0[3] += av * b0.w;
    a1[0] += av * b1.x; a1[1] += av * b1.y; a1[2] += av * b1.z; a1[3] += av * b1.w;
  }
  float* d = D + i * 36 + cbase;
#pragma unroll
  for (int r = 0; r < 4; ++r) { d[r] = a0[r]; d[4 + r] = a1[r]; }
}

__global__ __launch_bounds__(128) void k_ns(float* __restrict__ ws,
                                            const float* __restrict__ weight,
                                            const float* __restrict__ bias) {
  __shared__ float P[32 * 36], S[32 * 36], T1[32 * 36], T2[32 * 36];
  __shared__ float mean[32], msv[128], misc[1];
  const int tid = threadIdx.x;
  const int i = tid & 31;
  const int cbase = (tid >> 5) * 8; // lane owns row i, cols cbase..cbase+7
  const float inv_m = 1.0f / M_COLS;

  if (tid < 32) {
    float s = 0.f;
#pragma unroll
    for (int c = 0; c < 8; ++c) s += ws[WS_PART2 + c * 1056 + 1024 + tid];
    mean[tid] = s * inv_m;
  }
  __syncthreads();
#pragma unroll
  for (int q = 0; q < 8; ++q) {
    const int e = q * 128 + tid;
    float s = 0.f;
#pragma unroll
    for (int c = 0; c < 8; ++c) s += ws[WS_PART2 + c * 1056 + e];
    const int R = e >> 5, C = e & 31;
    S[R * 36 + C] = s * inv_m - mean[R] * mean[C] + ((R == C) ? EPS : 0.f);
  }
  __syncthreads();
  if (tid == 0) {
    float tr = 0.f;
#pragma unroll
    for (int k = 0; k < 32; ++k) tr += S[k * 36 + k];
    misc[0] = 1.0f / tr;
  }
  __syncthreads();
  const float tinv = misc[0];
#pragma unroll
  for (int q = 0; q < 8; ++q) {
    const int e = q * 128 + tid;
    const int R = e >> 5, C = e & 31;
    S[R * 36 + C] *= tinv;
    P[R * 36 + C] = (R == C) ? 1.f : 0.f;
  }
  __syncthreads();

  for (int it = 0; it < NS_ITERS; ++it) {
    mm32(T1, P, P, i, cbase);   // T1 = P^2
    __syncthreads();
    mm32(T2, T1, P, i, cbase);  // T2 = P^3
    __syncthreads();
    mm32(T1, T2, S, i, cbase);  // T1 = P^3 @ sigma_N
    __syncthreads();
#pragma unroll
    for (int cc = 0; cc < 8; ++cc) {
      const int c = cbase + cc;
      P[i * 36 + c] = 1.5f * P[i * 36 + c] - 0.5f * T1[i * 36 + c];
    }
    __syncthreads();
  }

  const float sq = sqrtf(tinv);
  float partd = 0.f;
#pragma unroll
  for (int cc = 0; cc < 8; ++cc) {
    const int c = cbase + cc;
    const float wmv = P[i * 36 + c] * sq;   // wm[i][c]
    ws[WS_WMT + c * 32 + i] = wmv;          // transposed: wmT[gp][g]
    partd += wmv * mean[c];
  }
  msv[tid] = partd;
  __syncthreads();
#pragma unroll
  for (int q = 0; q < 2; ++q) {
    const int c = q * 128 + tid;
    const int g = c & 31;
    const float m2 = msv[g] + msv[32 + g] + msv[64 + g] + msv[96 + g];
    ws[WS_SHIFT + c] = bias[c] - weight[c] * m2;
  }
}

// ---------------- Phase 3: apply (spill-free, nt stores) ----------------
__global__ __launch_bounds__(256, 4) void k_apply(const float* __restrict__ x,
                                                  const float* __restrict__ weight,
                                                  const float* __restrict__ ws,
                                                  float* __restrict__ out) {
  __shared__ float wmT[1024];   // [gp][g]
  __shared__ float wt[256], sh[256];
  const int tid = threadIdx.x;
  *(float4*)(wmT + tid * 4) = *(const float4*)(ws + WS_WMT + tid * 4);
  wt[tid] = weight[tid];
  sh[tid] = ws[WS_SHIFT + tid];
  __syncthreads();

  // 2 consecutive positions per thread; pairs never cross a panel (3136 even).
  const unsigned J = blockIdx.x * 512u + (unsigned)tid * 2u;
  const unsigned panel = J / HW_;
  const unsigned p = J - panel * HW_;
  const unsigned base = panel * PANEL_STRIDE + p;
  const int cb = (int)(panel & 7u) * 32;

  float2 acc[32];
#pragma unroll
  for (int g = 0; g < 32; ++g) { acc[g].x = 0.f; acc[g].y = 0.f; }

#pragma unroll 8
  for (int gp = 0; gp < 32; ++gp) {
    const float2 v = *(const float2*)(x + base + gp * HW_);
#pragma unroll
    for (int g4 = 0; g4 < 8; ++g4) {
      const float4 w = *(const float4*)(wmT + gp * 32 + g4 * 4); // uniform broadcast
      acc[g4 * 4 + 0].x += w.x * v.x; acc[g4 * 4 + 0].y += w.x * v.y;
      acc[g4 * 4 + 1].x += w.y * v.x; acc[g4 * 4 + 1].y += w.y * v.y;
      acc[g4 * 4 + 2].x += w.z * v.x; acc[g4 * 4 + 2].y += w.z * v.y;
      acc[g4 * 4 + 3].x += w.w * v.x; acc[g4 * 4 + 3].y += w.w * v.y;
    }
  }

#pragma unroll
  for (int g = 0; g < 32; ++g) {
    const int c = cb + g;
    f32x2v o;
    o.x = acc[g].x * wt[c] + sh[c];
    o.y = acc[g].y * wt[c] + sh[c];
    // nontemporal: don't allocate out in L2/L3, keep x resident for reads
    __builtin_nontemporal_store(o, (f32x2v*)(out + base + g * HW_));
  }
}

extern "C" void kernel_launch(void* const* d_in, const int* in_sizes, int n_in,
                              void* d_out, int out_size, void* d_ws, size_t ws_size,
                              hipStream_t stream) {
  const float* x = (const float*)d_in[0];
  const float* w = (const float*)d_in[1];
  const float* b = (const float*)d_in[2];
  float* out = (float*)d_out;
  float* ws = (float*)d_ws;

  hipLaunchKernelGGL(k_stats, dim3(NB1), dim3(256), 0, stream, x, ws);
  hipLaunchKernelGGL(k_reduce, dim3(33), dim3(256), 0, stream, ws);
  hipLaunchKernelGGL(k_ns, dim3(1), dim3(128), 0, stream, ws, w, b);
  hipLaunchKernelGGL(k_apply, dim3(3136), dim3(256), 0, stream, x, w, ws, out);
}